// Round 9
// baseline (191.601 us; speedup 1.0000x reference)
//
#include <hip/hip_runtime.h>
#include <hip/hip_cooperative_groups.h>
#include <math.h>
#include <stdint.h>

namespace cg = cooperative_groups;

#define NLAT 128
#define NLON 256
#define LMAX 50
#define MMAX 50
#define MGRID (NLAT*NLON)   // 32768
#define BATCH 2
#define NPTS 2048
#define NBKT 64
#define PI_F 3.14159265358979323846f

typedef float v2f __attribute__((ext_vector_type(2)));

__device__ __forceinline__ uint32_t umin32(uint32_t a, uint32_t b) { return a < b ? a : b; }
__device__ __forceinline__ uint32_t umax32(uint32_t a, uint32_t b) { return a > b ? a : b; }

// ---------------- shared building blocks (used by fused + fallback) --------

// NN phase body: one block handles (b, lon j). Writes f column. smem = raw LDS.
__device__ __forceinline__
void nn_body(char* smem, const float* __restrict__ target,
             float* __restrict__ f, int blk, int tid) {
    float2*   s_all  = (float2*)smem;                       // 16384
    float*    s_rall = (float*)(smem + 16384);              //  8192
    float2*   s_pt   = (float2*)(smem + 24576);             // 16448 (16-aligned)
    float*    s_rho  = (float*)(smem + 41024);              //  8224
    uint32_t* s_keys = (uint32_t*)(smem + 49248);           //  6144 [8][64][3]
    int*      cnt    = (int*)(smem + 55392);                //   256
    int*      start  = (int*)(smem + 55648);                //   260
    int*      cur    = (int*)(smem + 55908);                //   256
    int*      s_win  = (int*)(smem + 56164);                //     8

    int b = blk >> 8;
    int j = blk & 255;
    const float* tg = target + b * NPTS * 3;

    // phase 1: cart->sph (4 pts/thread) + bucket count
    if (tid < NBKT) cnt[tid] = 0;
    __syncthreads();
    float ph[4], py[4], rh[4]; int bk[4];
    #pragma unroll
    for (int c = 0; c < 4; ++c) {
        int p = tid + c * 512;
        float x = tg[p*3], y = tg[p*3+1], z = tg[p*3+2];
        float r = sqrtf(fmaf(x, x, fmaf(y, y, z*z)));
        float cc = fminf(1.f, fmaxf(-1.f, z / r));
        float pyv = acosf(cc) - PI_F;                       // [-pi, 0]
        ph[c] = atan2f(y, x); py[c] = pyv; rh[c] = r;
        int bb = (int)floorf((pyv + PI_F) * ((float)NBKT / PI_F));
        bk[c] = min(NBKT-1, max(0, bb));
        atomicAdd(&cnt[bk[c]], 1);
    }
    __syncthreads();
    if (tid == 0) {
        int s = 0;
        for (int i = 0; i < NBKT; ++i) { start[i] = s; cur[i] = s; s += cnt[i]; }
        start[NBKT] = s;
    }
    __syncthreads();
    #pragma unroll
    for (int c = 0; c < 4; ++c) {
        int pos = atomicAdd(&cur[bk[c]], 1);
        s_all[pos]  = make_float2(ph[c], py[c]);
        s_rall[pos] = rh[c];
    }

    // phase 2: block-uniform window via 64-lane parallel radius search
    float gy = (float)(j - 128) * (PI_F / 128.0f);
    int c0 = (int)floorf((gy + PI_F) * ((float)NBKT / PI_F));
    c0 = min(NBKT-1, max(0, c0));
    __syncthreads();
    if (tid < 64) {
        int t = tid;
        int lo_t = max(0, c0 - 5 - t), hi_t = min(NBKT-1, c0 + 5 + t);
        int cw_t = start[hi_t+1] - start[lo_t];
        unsigned long long ok =
            __ballot(cw_t >= 192 || (lo_t == 0 && hi_t == NBKT-1));
        int t0 = __ffsll((unsigned long long)ok) - 1;
        if (tid == 0) {
            s_win[0] = max(0, c0 - 5 - t0);
            s_win[1] = min(NBKT-1, c0 + 5 + t0);
        }
    }
    __syncthreads();
    int lo = s_win[0], hi = s_win[1];
    int cw = start[hi+1] - start[lo];
    int off = start[lo];
    for (int i = tid; i < cw; i += 512) {
        s_pt[i]  = s_all[off + i];
        s_rho[i] = s_rall[off + i];
    }
    int q = ((cw + 3) / 4 + 1) & ~1;                        // even, 4q>=cw
    for (int i = cw + tid; i < 4*q; i += 512) {
        s_pt[i] = make_float2(1e15f, 1e15f);                // sentinel
        s_rho[i] = 0.f;
    }
    __syncthreads();

    // phase 3: per-wave top-3 over its candidate partition
    int lane = tid & 63;
    int wv   = tid >> 6;
    int part = wv & 3;
    int lat  = lane + ((wv >> 2) << 6);
    float gx = (float)lat * (PI_F / 128.0f);
    v2f gx2 = {gx, gx}, gy2 = {gy, gy};
    uint32_t k0 = ~0u, k1 = ~0u, k2 = ~0u;
    uint32_t nb = (uint32_t)(part * q);
    const float4* p4 = (const float4*)(s_pt + part * q);
    int iters = q >> 1;
    #pragma unroll 4
    for (int i = 0; i < iters; ++i) {
        float4 Q = p4[i];                                   // wave-uniform b128
        v2f px = {Q.x, Q.z}, pyy = {Q.y, Q.w};
        v2f dp = gx2 - px, dt = gy2 - pyy;
        v2f d = dp * dp;
        d = dt * dt + d;
        uint32_t key0 = (__float_as_uint(d.x) & 0xFFFFF800u) | (nb + 2u*i);
        uint32_t key1 = (__float_as_uint(d.y) & 0xFFFFF800u) | (nb + 2u*i + 1u);
        uint32_t t1;
        t1 = umin32(umax32(key0, k0), k1);
        k2 = umin32(umax32(key0, k1), k2);
        k0 = umin32(key0, k0); k1 = t1;
        t1 = umin32(umax32(key1, k0), k1);
        k2 = umin32(umax32(key1, k1), k2);
        k0 = umin32(key1, k0); k1 = t1;
    }
    s_keys[(wv*64 + lane)*3 + 0] = k0;
    s_keys[(wv*64 + lane)*3 + 1] = k1;
    s_keys[(wv*64 + lane)*3 + 2] = k2;
    __syncthreads();

    // phase 4: merge partitions, weighted combine, write column
    if (tid < 128) {
        int lane2 = tid & 63;
        int half  = tid >> 6;
        uint32_t m0 = ~0u, m1 = ~0u, m2 = ~0u;
        #pragma unroll
        for (int w = half*4; w < half*4 + 4; ++w) {
            #pragma unroll
            for (int s = 0; s < 3; ++s) {
                uint32_t key = s_keys[(w*64 + lane2)*3 + s];
                uint32_t t1 = umin32(umax32(key, m0), m1);
                m2 = umin32(umax32(key, m1), m2);
                m0 = umin32(key, m0); m1 = t1;
            }
        }
        int i0 = m0 & 2047, i1 = m1 & 2047, i2 = m2 & 2047;
        int lat2 = lane2 + (half << 6);
        float gxs = (float)lat2 * (PI_F / 128.0f);
        float2 p0 = s_pt[i0], p1 = s_pt[i1], p2 = s_pt[i2];
        float e, r0, r1, r2;
        e = gxs - p0.x; r0 = e*e; e = gy - p0.y; r0 = sqrtf(fmaf(e, e, r0));
        e = gxs - p1.x; r1 = e*e; e = gy - p1.y; r1 = sqrtf(fmaf(e, e, r1));
        e = gxs - p2.x; r2 = e*e; e = gy - p2.y; r2 = sqrtf(fmaf(e, e, r2));
        float sum = r0 + r1 + r2;
        float interp = (s_rho[i0]*r0 + s_rho[i1]*r1 + s_rho[i2]*r2) / sum;
        f[b * MGRID + lat2 * NLON + j] = interp;
    }
}

// FFT+SHT phase body: one block handles (b, m) with 512 threads.
__device__ __forceinline__
void fftsht_body(char* smem, const float* __restrict__ f,
                 float* __restrict__ out, int blk, int tid) {
    float* Wl   = (float*)smem;                             // 50*129*4 = 25800
    float* red  = (float*)(smem + 25824);                   // 128*5*4  =  2560
    float* sFre = (float*)(smem + 28384);                   //   512
    float* cred = (float*)(smem + 28896);                   //  1024
    float* s_a  = (float*)(smem + 29920);                   //   200
    float* s_bb = (float*)(smem + 30120);                   //   200
    float* s_w  = (float*)(smem + 30320);                   //   512
    float* s_cm = (float*)(smem + 30832);                   //     4

    int b = blk / MMAX;
    int m = blk % MMAX;

    // precompute: a[l], bb[l] (tid 64-127), C(m) log-prefix (wave 0), w(k) (128-255)
    if (tid < 64) {
        int i = tid;
        float v = (i >= 1 && i <= m)
                  ? 0.5f * __log2f((2.f*i + 1.f) / (2.f*i)) : 0.f;
        #pragma unroll
        for (int sh = 1; sh < 64; sh <<= 1) v += __shfl_xor(v, sh);
        if (i == 0) *s_cm = ((m & 1) ? -1.f : 1.f) * exp2f(v);
    } else if (tid < 128) {
        int l = tid - 64;
        if (l < LMAX) {
            float fl = (float)l, fm2 = (float)(m*m);
            s_a[l]  = sqrtf((4.f*fl*fl - 1.f) / fmaxf(fl*fl - fm2, 0.25f));
            float flm1 = fl - 1.f;
            s_bb[l] = sqrtf(fmaxf(flm1*flm1 - fm2, 0.f) /
                            fmaxf(4.f*flm1*flm1 - 1.f, 0.25f));
        }
    } else if (tid < 256) {
        int k = tid - 128;
        float theta = (PI_F * (float)k) / 127.0f;
        float S = 0.0f;
        for (int kk = 1; kk <= 63; ++kk)
            S += 2.0f / (4.0f*kk*kk - 1.0f) * __cosf(2.0f * theta * (float)kk);
        float w = (2.0f/127.0f) * (1.0f - S);
        if (k == 0 || k == NLAT-1) w *= 0.5f;
        s_w[k] = w;
    }

    // partial DFT: k = tid>>2 (row), g = tid&3 (quarter), 16 float4 each
    {
        int k = tid >> 2, g = tid & 3;
        const float4* fb4 = (const float4*)(f + b * MGRID);
        float p = 0.0f;
        int a = (m * 64 * g) & 255;                         // (m*j) mod 256
        #pragma unroll
        for (int i = 0; i < 16; ++i) {
            float4 v = fb4[k * 64 + g * 16 + i];            // j = 64g + 4i
            p = fmaf(v.x, __cosf((float)a * (2.0f*PI_F/256.0f)), p); a = (a + m) & 255;
            p = fmaf(v.y, __cosf((float)a * (2.0f*PI_F/256.0f)), p); a = (a + m) & 255;
            p = fmaf(v.z, __cosf((float)a * (2.0f*PI_F/256.0f)), p); a = (a + m) & 255;
            p = fmaf(v.w, __cosf((float)a * (2.0f*PI_F/256.0f)), p); a = (a + m) & 255;
        }
        red[k * 5 + g] = p;
    }
    __syncthreads();

    // row-sum -> sFre; build Wl via shared recurrence coeffs
    if (tid < NLAT) {
        int k = tid;
        float srow = red[k*5] + red[k*5+1] + red[k*5+2] + red[k*5+3];
        sFre[k] = srow * (2.0f * PI_F / 256.0f);

        float theta = (PI_F * (float)k) / 127.0f;
        float x = __cosf(theta), sn = __sinf(theta);
        float w = s_w[k];
        float pmm;
        if (m == 0) pmm = 0.28209479177f;
        else {
            float mag = exp2f((float)m * __log2f(fabsf(sn)));
            float sg  = (sn < 0.f && (m & 1)) ? -1.f : 1.f;
            pmm = 0.28209479177f * (*s_cm) * mag * sg;
        }
        for (int l = 0; l < m; ++l) Wl[l*129 + k] = 0.0f;
        float Plm2 = pmm;
        Wl[m*129 + k] = Plm2 * w;
        if (m + 1 < LMAX) {
            float Plm1 = sqrtf(2.0f*m + 3.0f) * x * pmm;
            Wl[(m+1)*129 + k] = Plm1 * w;
            for (int l = m + 2; l < LMAX; ++l) {
                float P = s_a[l] * fmaf(-s_bb[l], Plm2, x * Plm1);
                Wl[l*129 + k] = P * w;
                Plm2 = Plm1; Plm1 = P;
            }
        }
    }
    __syncthreads();

    // contraction: out[b,l,m] = sum_k Wl[l][k] * sFre[k]
    float acc = 0.0f;
    if (tid < 200) {
        int l = tid >> 2, kq = tid & 3;
        #pragma unroll 8
        for (int i = 0; i < 32; ++i)
            acc = fmaf(Wl[l*129 + kq*32 + i], sFre[kq*32 + i], acc);
    }
    if (tid < 256) cred[tid] = acc;
    __syncthreads();
    if (tid < LMAX)
        out[(b*LMAX + tid)*MMAX + m] =
            cred[4*tid] + cred[4*tid+1] + cred[4*tid+2] + cred[4*tid+3];
}

// ---------------- fused cooperative kernel --------------------------------
// 512 blocks x 512 threads, 2 blocks/CU (LDS 56.2KB x2 = 112.4 < 160KB;
// launch_bounds(512,4) caps VGPR at 128 -> 4 waves/SIMD). Blocks 0-511 do
// NN, grid-sync, then blocks 0-99 do the (b,m) fftsht tasks.
__global__ __launch_bounds__(512, 4)
void k_fused(const float* __restrict__ target, float* __restrict__ f,
             float* __restrict__ out) {
    __shared__ __attribute__((aligned(16))) char smem[56192];
    int tid = threadIdx.x;
    nn_body(smem, target, f, blockIdx.x, tid);
    __threadfence();                       // f visible device-wide
    cg::this_grid().sync();
    if (blockIdx.x < BATCH * MMAX)
        fftsht_body(smem, f, out, blockIdx.x, tid);
}

// ---------------- fallback pair (r8-proven path) ---------------------------
__global__ __launch_bounds__(512, 2)
void k_nn(const float* __restrict__ target, float* __restrict__ f) {
    __shared__ __attribute__((aligned(16))) char smem[56192];
    nn_body(smem, target, f, blockIdx.x, threadIdx.x);
}
__global__ __launch_bounds__(512)
void k_fftsht(const float* __restrict__ f, float* __restrict__ out) {
    __shared__ __attribute__((aligned(16))) char smem[30848];
    fftsht_body(smem, f, out, blockIdx.x, threadIdx.x);
}

extern "C" void kernel_launch(void* const* d_in, const int* in_sizes, int n_in,
                              void* d_out, int out_size, void* d_ws, size_t ws_size,
                              hipStream_t stream) {
    const float* target = (const float*)d_in[0];
    float* out = (float*)d_out;
    float* f   = (float*)d_ws;                       // B*MGRID floats = 256 KB

    void* args[] = { (void*)&target, (void*)&f, (void*)&out };
    hipError_t err = hipLaunchCooperativeKernel(
        (const void*)k_fused, dim3(BATCH*NLON), dim3(512), args, 0, stream);
    if (err != hipSuccess) {                         // deterministic fallback
        k_nn<<<BATCH*NLON, 512, 0, stream>>>(target, f);
        k_fftsht<<<BATCH*MMAX, 512, 0, stream>>>(f, out);
    }
}

// Round 10
// 121.324 us; speedup vs baseline: 1.5793x; 1.5793x over previous
//
#include <hip/hip_runtime.h>
#include <math.h>
#include <stdint.h>

#define NLAT 128
#define NLON 256
#define LMAX 50
#define MMAX 50
#define MGRID (NLAT*NLON)   // 32768
#define BATCH 2
#define NPTS 2048
#define NBKT 64
#define PI_F 3.14159265358979323846f
#define FLAG_MAGIC 0x5EED1234

typedef float v2f __attribute__((ext_vector_type(2)));

__device__ __forceinline__ uint32_t umin32(uint32_t a, uint32_t b) { return a < b ? a : b; }
__device__ __forceinline__ uint32_t umax32(uint32_t a, uint32_t b) { return a > b ? a : b; }

// ---------------- NN phase body (verified r8/r9): block handles (b, lon j) ----
__device__ __forceinline__
void nn_body(char* smem, const float* __restrict__ target,
             float* __restrict__ f, int blk, int tid) {
    float2*   s_all  = (float2*)smem;                       // 16384
    float*    s_rall = (float*)(smem + 16384);              //  8192
    float2*   s_pt   = (float2*)(smem + 24576);             // 16448 (16-aligned)
    float*    s_rho  = (float*)(smem + 41024);              //  8224
    uint32_t* s_keys = (uint32_t*)(smem + 49248);           //  6144 [8][64][3]
    int*      cnt    = (int*)(smem + 55392);                //   256
    int*      start  = (int*)(smem + 55648);                //   260
    int*      cur    = (int*)(smem + 55908);                //   256
    int*      s_win  = (int*)(smem + 56164);                //     8

    int b = blk >> 8;
    int j = blk & 255;
    const float* tg = target + b * NPTS * 3;

    // phase 1: cart->sph (4 pts/thread) + bucket count
    if (tid < NBKT) cnt[tid] = 0;
    __syncthreads();
    float ph[4], py[4], rh[4]; int bk[4];
    #pragma unroll
    for (int c = 0; c < 4; ++c) {
        int p = tid + c * 512;
        float x = tg[p*3], y = tg[p*3+1], z = tg[p*3+2];
        float r = sqrtf(fmaf(x, x, fmaf(y, y, z*z)));
        float cc = fminf(1.f, fmaxf(-1.f, z / r));
        float pyv = acosf(cc) - PI_F;                       // [-pi, 0]
        ph[c] = atan2f(y, x); py[c] = pyv; rh[c] = r;
        int bb = (int)floorf((pyv + PI_F) * ((float)NBKT / PI_F));
        bk[c] = min(NBKT-1, max(0, bb));
        atomicAdd(&cnt[bk[c]], 1);
    }
    __syncthreads();
    if (tid == 0) {
        int s = 0;
        for (int i = 0; i < NBKT; ++i) { start[i] = s; cur[i] = s; s += cnt[i]; }
        start[NBKT] = s;
    }
    __syncthreads();
    #pragma unroll
    for (int c = 0; c < 4; ++c) {
        int pos = atomicAdd(&cur[bk[c]], 1);
        s_all[pos]  = make_float2(ph[c], py[c]);
        s_rall[pos] = rh[c];
    }

    // phase 2: block-uniform window via 64-lane parallel radius search
    float gy = (float)(j - 128) * (PI_F / 128.0f);
    int c0 = (int)floorf((gy + PI_F) * ((float)NBKT / PI_F));
    c0 = min(NBKT-1, max(0, c0));
    __syncthreads();
    if (tid < 64) {
        int t = tid;
        int lo_t = max(0, c0 - 5 - t), hi_t = min(NBKT-1, c0 + 5 + t);
        int cw_t = start[hi_t+1] - start[lo_t];
        unsigned long long ok =
            __ballot(cw_t >= 192 || (lo_t == 0 && hi_t == NBKT-1));
        int t0 = __ffsll((unsigned long long)ok) - 1;
        if (tid == 0) {
            s_win[0] = max(0, c0 - 5 - t0);
            s_win[1] = min(NBKT-1, c0 + 5 + t0);
        }
    }
    __syncthreads();
    int lo = s_win[0], hi = s_win[1];
    int cw = start[hi+1] - start[lo];
    int off = start[lo];
    for (int i = tid; i < cw; i += 512) {
        s_pt[i]  = s_all[off + i];
        s_rho[i] = s_rall[off + i];
    }
    int q = ((cw + 3) / 4 + 1) & ~1;                        // even, 4q>=cw
    for (int i = cw + tid; i < 4*q; i += 512) {
        s_pt[i] = make_float2(1e15f, 1e15f);                // sentinel
        s_rho[i] = 0.f;
    }
    __syncthreads();

    // phase 3: per-wave top-3 over its candidate partition
    int lane = tid & 63;
    int wv   = tid >> 6;
    int part = wv & 3;
    int lat  = lane + ((wv >> 2) << 6);
    float gx = (float)lat * (PI_F / 128.0f);
    v2f gx2 = {gx, gx}, gy2 = {gy, gy};
    uint32_t k0 = ~0u, k1 = ~0u, k2 = ~0u;
    uint32_t nb = (uint32_t)(part * q);
    const float4* p4 = (const float4*)(s_pt + part * q);
    int iters = q >> 1;
    #pragma unroll 4
    for (int i = 0; i < iters; ++i) {
        float4 Q = p4[i];                                   // wave-uniform b128
        v2f px = {Q.x, Q.z}, pyy = {Q.y, Q.w};
        v2f dp = gx2 - px, dt = gy2 - pyy;
        v2f d = dp * dp;
        d = dt * dt + d;
        uint32_t key0 = (__float_as_uint(d.x) & 0xFFFFF800u) | (nb + 2u*i);
        uint32_t key1 = (__float_as_uint(d.y) & 0xFFFFF800u) | (nb + 2u*i + 1u);
        uint32_t t1;
        t1 = umin32(umax32(key0, k0), k1);
        k2 = umin32(umax32(key0, k1), k2);
        k0 = umin32(key0, k0); k1 = t1;
        t1 = umin32(umax32(key1, k0), k1);
        k2 = umin32(umax32(key1, k1), k2);
        k0 = umin32(key1, k0); k1 = t1;
    }
    s_keys[(wv*64 + lane)*3 + 0] = k0;
    s_keys[(wv*64 + lane)*3 + 1] = k1;
    s_keys[(wv*64 + lane)*3 + 2] = k2;
    __syncthreads();

    // phase 4: merge partitions, weighted combine, write column
    if (tid < 128) {
        int lane2 = tid & 63;
        int half  = tid >> 6;
        uint32_t m0 = ~0u, m1 = ~0u, m2 = ~0u;
        #pragma unroll
        for (int w = half*4; w < half*4 + 4; ++w) {
            #pragma unroll
            for (int s = 0; s < 3; ++s) {
                uint32_t key = s_keys[(w*64 + lane2)*3 + s];
                uint32_t t1 = umin32(umax32(key, m0), m1);
                m2 = umin32(umax32(key, m1), m2);
                m0 = umin32(key, m0); m1 = t1;
            }
        }
        int i0 = m0 & 2047, i1 = m1 & 2047, i2 = m2 & 2047;
        int lat2 = lane2 + (half << 6);
        float gxs = (float)lat2 * (PI_F / 128.0f);
        float2 p0 = s_pt[i0], p1 = s_pt[i1], p2 = s_pt[i2];
        float e, r0, r1, r2;
        e = gxs - p0.x; r0 = e*e; e = gy - p0.y; r0 = sqrtf(fmaf(e, e, r0));
        e = gxs - p1.x; r1 = e*e; e = gy - p1.y; r1 = sqrtf(fmaf(e, e, r1));
        e = gxs - p2.x; r2 = e*e; e = gy - p2.y; r2 = sqrtf(fmaf(e, e, r2));
        float sum = r0 + r1 + r2;
        float interp = (s_rho[i0]*r0 + s_rho[i1]*r1 + s_rho[i2]*r2) / sum;
        f[b * MGRID + lat2 * NLON + j] = interp;
    }
}

// ---------------- FFT+SHT phase body (verified r9): block handles (b, m) ----
__device__ __forceinline__
void fftsht_body(char* smem, const float* __restrict__ f,
                 float* __restrict__ out, int blk, int tid) {
    float* Wl   = (float*)smem;                             // 25800
    float* red  = (float*)(smem + 25824);                   //  2560
    float* sFre = (float*)(smem + 28384);                   //   512
    float* cred = (float*)(smem + 28896);                   //  1024
    float* s_a  = (float*)(smem + 29920);                   //   200
    float* s_bb = (float*)(smem + 30120);                   //   200
    float* s_w  = (float*)(smem + 30320);                   //   512
    float* s_cm = (float*)(smem + 30832);                   //     4

    int b = blk / MMAX;
    int m = blk % MMAX;

    if (tid < 64) {                                         // C(m) log-prefix
        int i = tid;
        float v = (i >= 1 && i <= m)
                  ? 0.5f * __log2f((2.f*i + 1.f) / (2.f*i)) : 0.f;
        #pragma unroll
        for (int sh = 1; sh < 64; sh <<= 1) v += __shfl_xor(v, sh);
        if (i == 0) *s_cm = ((m & 1) ? -1.f : 1.f) * exp2f(v);
    } else if (tid < 128) {                                 // a[l], bb[l]
        int l = tid - 64;
        if (l < LMAX) {
            float fl = (float)l, fm2 = (float)(m*m);
            s_a[l]  = sqrtf((4.f*fl*fl - 1.f) / fmaxf(fl*fl - fm2, 0.25f));
            float flm1 = fl - 1.f;
            s_bb[l] = sqrtf(fmaxf(flm1*flm1 - fm2, 0.f) /
                            fmaxf(4.f*flm1*flm1 - 1.f, 0.25f));
        }
    } else if (tid < 256) {                                 // CC weights w(k)
        int k = tid - 128;
        float theta = (PI_F * (float)k) / 127.0f;
        float S = 0.0f;
        for (int kk = 1; kk <= 63; ++kk)
            S += 2.0f / (4.0f*kk*kk - 1.0f) * __cosf(2.0f * theta * (float)kk);
        float w = (2.0f/127.0f) * (1.0f - S);
        if (k == 0 || k == NLAT-1) w *= 0.5f;
        s_w[k] = w;
    }

    // partial DFT: k = tid>>2 (row), g = tid&3 (quarter), 16 float4 each
    {
        int k = tid >> 2, g = tid & 3;
        const float4* fb4 = (const float4*)(f + b * MGRID);
        float p = 0.0f;
        int a = (m * 64 * g) & 255;                         // (m*j) mod 256
        #pragma unroll
        for (int i = 0; i < 16; ++i) {
            float4 v = fb4[k * 64 + g * 16 + i];            // j = 64g + 4i
            p = fmaf(v.x, __cosf((float)a * (2.0f*PI_F/256.0f)), p); a = (a + m) & 255;
            p = fmaf(v.y, __cosf((float)a * (2.0f*PI_F/256.0f)), p); a = (a + m) & 255;
            p = fmaf(v.z, __cosf((float)a * (2.0f*PI_F/256.0f)), p); a = (a + m) & 255;
            p = fmaf(v.w, __cosf((float)a * (2.0f*PI_F/256.0f)), p); a = (a + m) & 255;
        }
        red[k * 5 + g] = p;
    }
    __syncthreads();

    // row-sum -> sFre; build Wl via shared recurrence coeffs
    if (tid < NLAT) {
        int k = tid;
        float srow = red[k*5] + red[k*5+1] + red[k*5+2] + red[k*5+3];
        sFre[k] = srow * (2.0f * PI_F / 256.0f);

        float theta = (PI_F * (float)k) / 127.0f;
        float x = __cosf(theta), sn = __sinf(theta);
        float w = s_w[k];
        float pmm;
        if (m == 0) pmm = 0.28209479177f;
        else {
            float mag = exp2f((float)m * __log2f(fabsf(sn)));
            float sg  = (sn < 0.f && (m & 1)) ? -1.f : 1.f;
            pmm = 0.28209479177f * (*s_cm) * mag * sg;
        }
        for (int l = 0; l < m; ++l) Wl[l*129 + k] = 0.0f;
        float Plm2 = pmm;
        Wl[m*129 + k] = Plm2 * w;
        if (m + 1 < LMAX) {
            float Plm1 = sqrtf(2.0f*m + 3.0f) * x * pmm;
            Wl[(m+1)*129 + k] = Plm1 * w;
            for (int l = m + 2; l < LMAX; ++l) {
                float P = s_a[l] * fmaf(-s_bb[l], Plm2, x * Plm1);
                Wl[l*129 + k] = P * w;
                Plm2 = Plm1; Plm1 = P;
            }
        }
    }
    __syncthreads();

    // contraction: out[b,l,m] = sum_k Wl[l][k] * sFre[k]
    float acc = 0.0f;
    if (tid < 200) {
        int l = tid >> 2, kq = tid & 3;
        #pragma unroll 8
        for (int i = 0; i < 32; ++i)
            acc = fmaf(Wl[l*129 + kq*32 + i], sFre[kq*32 + i], acc);
    }
    if (tid < 256) cred[tid] = acc;
    __syncthreads();
    if (tid < LMAX)
        out[(b*LMAX + tid)*MMAX + m] =
            cred[4*tid] + cred[4*tid+1] + cred[4*tid+2] + cred[4*tid+3];
}

// ---------------- single fused kernel with lean flag barrier ---------------
// 256 blocks x 512 threads, guaranteed co-resident (<= 1 block/CU needed;
// LDS 56.3KB < 160KB, 8 waves < 32, launch_bounds caps VGPR at 128).
// Block j: NN for (b=0,j) then (b=1,j); publish flags[j]=MAGIC (agent
// release). Blocks 0-99 then acquire-spin on all 256 flags (one per lane,
// s_sleep backoff) and run the (b,m) fftsht task. No cg grid-sync (r9
// showed it costs ~120us on gfx950); producers all resident -> no deadlock.
__global__ __launch_bounds__(512, 4)
void k_fused(const float* __restrict__ target, float* __restrict__ f,
             int* __restrict__ flags, float* __restrict__ out) {
    __shared__ __attribute__((aligned(16))) char smem[56192];
    int tid = threadIdx.x;
    int j = blockIdx.x;                                  // 0..255
    nn_body(smem, target, f, j, tid);                    // batch 0
    __syncthreads();
    nn_body(smem, target, f, 256 + j, tid);              // batch 1
    __threadfence();                                     // publish f stores
    __syncthreads();
    if (tid == 0)
        __hip_atomic_store(&flags[j], FLAG_MAGIC,
                           __ATOMIC_RELEASE, __HIP_MEMORY_SCOPE_AGENT);
    if (blockIdx.x >= BATCH * MMAX) return;              // 156 blocks exit

    if (tid < 256) {                                     // lane t waits col t
        int spins = 0;
        while (__hip_atomic_load(&flags[tid], __ATOMIC_ACQUIRE,
                                 __HIP_MEMORY_SCOPE_AGENT) != FLAG_MAGIC
               && spins < 2000000) {                     // bounded (~0.5s) guard
            __builtin_amdgcn_s_sleep(8);
            ++spins;
        }
    }
    __syncthreads();
    fftsht_body(smem, f, out, blockIdx.x, tid);
}

extern "C" void kernel_launch(void* const* d_in, const int* in_sizes, int n_in,
                              void* d_out, int out_size, void* d_ws, size_t ws_size,
                              hipStream_t stream) {
    const float* target = (const float*)d_in[0];
    float* out = (float*)d_out;
    float* f   = (float*)d_ws;                           // 65536 floats
    int* flags = (int*)((char*)d_ws + BATCH*MGRID*sizeof(float)); // 256 ints

    k_fused<<<256, 512, 0, stream>>>(target, f, flags, out);
}

// Round 11
// 74.754 us; speedup vs baseline: 2.5631x; 1.6230x over previous
//
#include <hip/hip_runtime.h>
#include <math.h>
#include <stdint.h>

#define NLAT 128
#define NLON 256
#define LMAX 50
#define MMAX 50
#define MGRID (NLAT*NLON)   // 32768
#define BATCH 2
#define NPTS 2048
#define NBKT 64
#define PI_F 3.14159265358979323846f

typedef float v2f __attribute__((ext_vector_type(2)));

__device__ __forceinline__ uint32_t umin32(uint32_t a, uint32_t b) { return a < b ? a : b; }
__device__ __forceinline__ uint32_t umax32(uint32_t a, uint32_t b) { return a > b ? a : b; }

// ============ kernel 1: fused cart->sph + theta counting-sort + windowed
// 3-NN + weighted combine -> f. One block per (b, lon j); 8 waves =
// (lat half) x (4 candidate partitions). Phase 3 indexes the sorted array
// DIRECTLY (no window copy); parallel wave-0 prefix scan.
__global__ __launch_bounds__(512, 2)
void k_nn(const float* __restrict__ target, float* __restrict__ f) {
    __shared__ __attribute__((aligned(16))) float2 s_all[NPTS + 8];
    __shared__ float    s_rall[NPTS + 8];
    __shared__ uint32_t s_keys[8*64*3];
    __shared__ int      cnt[NBKT], start[NBKT + 1], cur[NBKT];
    __shared__ int      s_win[2];
    int b = blockIdx.x >> 8;
    int j = blockIdx.x & 255;
    int tid = threadIdx.x;
    const float* tg = target + b * NPTS * 3;

    // ---- phase 1: cart->sph (4 pts/thread) + bucket count
    if (tid < NBKT) cnt[tid] = 0;
    __syncthreads();
    float ph[4], py[4], rh[4]; int bk[4];
    #pragma unroll
    for (int c = 0; c < 4; ++c) {
        int p = tid + c * 512;
        float x = tg[p*3], y = tg[p*3+1], z = tg[p*3+2];
        float r = sqrtf(fmaf(x, x, fmaf(y, y, z*z)));
        float cc = fminf(1.f, fmaxf(-1.f, z / r));
        float pyv = acosf(cc) - PI_F;                       // [-pi, 0]
        ph[c] = atan2f(y, x); py[c] = pyv; rh[c] = r;
        int bb = (int)floorf((pyv + PI_F) * ((float)NBKT / PI_F));
        bk[c] = min(NBKT-1, max(0, bb));
        atomicAdd(&cnt[bk[c]], 1);
    }
    __syncthreads();

    // ---- phase 2a: wave-0 parallel prefix scan of bucket counts
    if (tid < 64) {
        int v = cnt[tid];
        int cv = v;
        #pragma unroll
        for (int sh = 1; sh < 64; sh <<= 1) {
            int t = __shfl_up(v, sh);
            if (tid >= sh) v += t;
        }
        start[tid + 1] = v;                                 // inclusive
        cur[tid] = v - cv;                                  // exclusive
        if (tid == 0) start[0] = 0;
    }
    __syncthreads();

    // ---- phase 2b: scatter into sorted order + sentinel pad; window ballot
    #pragma unroll
    for (int c = 0; c < 4; ++c) {
        int pos = atomicAdd(&cur[bk[c]], 1);
        s_all[pos]  = make_float2(ph[c], py[c]);
        s_rall[pos] = rh[c];
    }
    if (tid < 8) {
        s_all[NPTS + tid] = make_float2(1e15f, 1e15f);      // sentinel
        s_rall[NPTS + tid] = 0.f;
    }
    float gy = (float)(j - 128) * (PI_F / 128.0f);
    int c0 = (int)floorf((gy + PI_F) * ((float)NBKT / PI_F));
    c0 = min(NBKT-1, max(0, c0));
    if (tid < 64) {                                         // start[] final
        int t = tid;
        int lo_t = max(0, c0 - 5 - t), hi_t = min(NBKT-1, c0 + 5 + t);
        int cw_t = start[hi_t+1] - start[lo_t];
        unsigned long long ok =
            __ballot(cw_t >= 192 || (lo_t == 0 && hi_t == NBKT-1));
        int t0 = __ffsll((unsigned long long)ok) - 1;
        if (tid == 0) {
            s_win[0] = max(0, c0 - 5 - t0);
            s_win[1] = min(NBKT-1, c0 + 5 + t0);
        }
    }
    __syncthreads();

    // ---- phase 3: per-wave top-3 over its partition of the sorted window
    int lo = s_win[0], hi = s_win[1];
    int off = start[lo] & ~1;                               // even: float4 align
    int cw  = start[hi+1] - off;                            // <= 2048
    int q = ((cw + 3) / 4 + 1) & ~1;                        // even, 4q >= cw
    int lane = tid & 63;
    int wv   = tid >> 6;
    int part = wv & 3;
    int lat  = lane + ((wv >> 2) << 6);
    float gx = (float)lat * (PI_F / 128.0f);
    v2f gx2 = {gx, gx}, gy2 = {gy, gy};
    uint32_t k0 = ~0u, k1 = ~0u, k2 = ~0u;
    uint32_t nb = (uint32_t)(part * q);
    const float4* p4 = (const float4*)(s_all + off + part * q);
    int iters = q >> 1;
    #pragma unroll 4
    for (int i = 0; i < iters; ++i) {
        float4 Q = p4[i];                                   // wave-uniform b128
        v2f px = {Q.x, Q.z}, pyy = {Q.y, Q.w};
        v2f dp = gx2 - px, dt = gy2 - pyy;
        v2f d = dp * dp;
        d = dt * dt + d;
        uint32_t key0 = (__float_as_uint(d.x) & 0xFFFFF800u) | (nb + 2u*i);
        uint32_t key1 = (__float_as_uint(d.y) & 0xFFFFF800u) | (nb + 2u*i + 1u);
        uint32_t t1;
        t1 = umin32(umax32(key0, k0), k1);
        k2 = umin32(umax32(key0, k1), k2);
        k0 = umin32(key0, k0); k1 = t1;
        t1 = umin32(umax32(key1, k0), k1);
        k2 = umin32(umax32(key1, k1), k2);
        k0 = umin32(key1, k0); k1 = t1;
    }
    s_keys[(wv*64 + lane)*3 + 0] = k0;
    s_keys[(wv*64 + lane)*3 + 1] = k1;
    s_keys[(wv*64 + lane)*3 + 2] = k2;
    __syncthreads();

    // ---- phase 4: merge partitions, weighted combine, write column
    if (tid < 128) {
        int lane2 = tid & 63;
        int half  = tid >> 6;
        uint32_t m0 = ~0u, m1 = ~0u, m2 = ~0u;
        #pragma unroll
        for (int w = half*4; w < half*4 + 4; ++w) {
            #pragma unroll
            for (int s = 0; s < 3; ++s) {
                uint32_t key = s_keys[(w*64 + lane2)*3 + s];
                uint32_t t1 = umin32(umax32(key, m0), m1);
                m2 = umin32(umax32(key, m1), m2);
                m0 = umin32(key, m0); m1 = t1;
            }
        }
        int i0 = off + (int)(m0 & 2047);
        int i1 = off + (int)(m1 & 2047);
        int i2 = off + (int)(m2 & 2047);
        int lat2 = lane2 + (half << 6);
        float gxs = (float)lat2 * (PI_F / 128.0f);
        float2 p0 = s_all[i0], p1 = s_all[i1], p2 = s_all[i2];
        float e, r0, r1, r2;
        e = gxs - p0.x; r0 = e*e; e = gy - p0.y; r0 = sqrtf(fmaf(e, e, r0));
        e = gxs - p1.x; r1 = e*e; e = gy - p1.y; r1 = sqrtf(fmaf(e, e, r1));
        e = gxs - p2.x; r2 = e*e; e = gy - p2.y; r2 = sqrtf(fmaf(e, e, r2));
        float sum = r0 + r1 + r2;
        float interp = (s_rall[i0]*r0 + s_rall[i1]*r1 + s_rall[i2]*r2) / sum;
        f[b * MGRID + lat2 * NLON + j] = interp;
    }
}

// ============ kernel 2: fused W-gen + truncated-DFT + Legendre contraction
// (r10-field-verified 512-thread body). One block per (b, m).
__global__ __launch_bounds__(512)
void k_fftsht(const float* __restrict__ f, float* __restrict__ out) {
    __shared__ float Wl[LMAX*129];                   // 25800
    __shared__ float red[NLAT*5];                    //  2560
    __shared__ float sFre[NLAT];
    __shared__ float cred[256];
    __shared__ float s_a[LMAX], s_bb[LMAX], s_w[NLAT];
    __shared__ float s_cm;
    int b = blockIdx.x / MMAX;
    int m = blockIdx.x % MMAX;
    int tid = threadIdx.x;

    if (tid < 64) {                                  // C(m) log-prefix product
        int i = tid;
        float v = (i >= 1 && i <= m)
                  ? 0.5f * __log2f((2.f*i + 1.f) / (2.f*i)) : 0.f;
        #pragma unroll
        for (int sh = 1; sh < 64; sh <<= 1) v += __shfl_xor(v, sh);
        if (i == 0) s_cm = ((m & 1) ? -1.f : 1.f) * exp2f(v);
    } else if (tid < 128) {                          // recurrence coeffs a, bb
        int l = tid - 64;
        if (l < LMAX) {
            float fl = (float)l, fm2 = (float)(m*m);
            s_a[l]  = sqrtf((4.f*fl*fl - 1.f) / fmaxf(fl*fl - fm2, 0.25f));
            float flm1 = fl - 1.f;
            s_bb[l] = sqrtf(fmaxf(flm1*flm1 - fm2, 0.f) /
                            fmaxf(4.f*flm1*flm1 - 1.f, 0.25f));
        }
    } else if (tid < 256) {                          // CC weights w(k)
        int k = tid - 128;
        float theta = (PI_F * (float)k) / 127.0f;
        float S = 0.0f;
        for (int kk = 1; kk <= 63; ++kk)
            S += 2.0f / (4.0f*kk*kk - 1.0f) * __cosf(2.0f * theta * (float)kk);
        float w = (2.0f/127.0f) * (1.0f - S);
        if (k == 0 || k == NLAT-1) w *= 0.5f;
        s_w[k] = w;
    }

    // partial DFT: k = tid>>2 (row), g = tid&3 (quarter), 16 float4 each
    {
        int k = tid >> 2, g = tid & 3;
        const float4* fb4 = (const float4*)(f + b * MGRID);
        float p = 0.0f;
        int a = (m * 64 * g) & 255;                  // (m*j) mod 256
        #pragma unroll
        for (int i = 0; i < 16; ++i) {
            float4 v = fb4[k * 64 + g * 16 + i];     // j = 64g + 4i
            p = fmaf(v.x, __cosf((float)a * (2.0f*PI_F/256.0f)), p); a = (a + m) & 255;
            p = fmaf(v.y, __cosf((float)a * (2.0f*PI_F/256.0f)), p); a = (a + m) & 255;
            p = fmaf(v.z, __cosf((float)a * (2.0f*PI_F/256.0f)), p); a = (a + m) & 255;
            p = fmaf(v.w, __cosf((float)a * (2.0f*PI_F/256.0f)), p); a = (a + m) & 255;
        }
        red[k * 5 + g] = p;
    }
    __syncthreads();

    // row-sum -> sFre; build Wl via shared recurrence coeffs
    if (tid < NLAT) {
        int k = tid;
        float srow = red[k*5] + red[k*5+1] + red[k*5+2] + red[k*5+3];
        sFre[k] = srow * (2.0f * PI_F / 256.0f);

        float theta = (PI_F * (float)k) / 127.0f;
        float x = __cosf(theta), sn = __sinf(theta);
        float w = s_w[k];
        float pmm;
        if (m == 0) pmm = 0.28209479177f;
        else {
            float mag = exp2f((float)m * __log2f(fabsf(sn)));
            float sg  = (sn < 0.f && (m & 1)) ? -1.f : 1.f;
            pmm = 0.28209479177f * s_cm * mag * sg;
        }
        for (int l = 0; l < m; ++l) Wl[l*129 + k] = 0.0f;
        float Plm2 = pmm;
        Wl[m*129 + k] = Plm2 * w;
        if (m + 1 < LMAX) {
            float Plm1 = sqrtf(2.0f*m + 3.0f) * x * pmm;
            Wl[(m+1)*129 + k] = Plm1 * w;
            for (int l = m + 2; l < LMAX; ++l) {
                float P = s_a[l] * fmaf(-s_bb[l], Plm2, x * Plm1);
                Wl[l*129 + k] = P * w;
                Plm2 = Plm1; Plm1 = P;
            }
        }
    }
    __syncthreads();

    // contraction: out[b,l,m] = sum_k Wl[l][k] * sFre[k]
    float acc = 0.0f;
    if (tid < 200) {
        int l = tid >> 2, kq = tid & 3;
        #pragma unroll 8
        for (int i = 0; i < 32; ++i)
            acc = fmaf(Wl[l*129 + kq*32 + i], sFre[kq*32 + i], acc);
    }
    if (tid < 256) cred[tid] = acc;
    __syncthreads();
    if (tid < LMAX)
        out[(b*LMAX + tid)*MMAX + m] =
            cred[4*tid] + cred[4*tid+1] + cred[4*tid+2] + cred[4*tid+3];
}

extern "C" void kernel_launch(void* const* d_in, const int* in_sizes, int n_in,
                              void* d_out, int out_size, void* d_ws, size_t ws_size,
                              hipStream_t stream) {
    const float* target = (const float*)d_in[0];
    float* out = (float*)d_out;
    float* f   = (float*)d_ws;                       // B*MGRID floats = 256 KB

    k_nn<<<BATCH*NLON, 512, 0, stream>>>(target, f);
    k_fftsht<<<BATCH*MMAX, 512, 0, stream>>>(f, out);
}